// Round 21
// baseline (1511.526 us; speedup 1.0000x reference)
//
#include <hip/hip_runtime.h>

#define TLEN  1024
#define HID   96
#define NSAMP 16
#define NTHR  768     // 12 waves = 3/SIMD: third wave fills latency bubbles
#define XSTR  1025
#define OSTR  1025
#define HSTR  104
#define HBUF  (NSAMP * HSTR)

typedef _Float16 f16x8 __attribute__((ext_vector_type(8)));
typedef float    f32x4 __attribute__((ext_vector_type(4)));

// HW v_exp_f32 (2^x) + v_rcp_f32 nonlinearities (R20-proven, -41%)
__device__ __forceinline__ float sigf(float v) {
    float e = __builtin_amdgcn_exp2f(v * -1.44269504089f);   // exp(-v)
    return __builtin_amdgcn_rcpf(1.0f + e);
}
__device__ __forceinline__ float tanh_fast(float v) {
    float e = __builtin_amdgcn_exp2f(v * 2.88539008178f);    // exp(2v)
    return fmaf(-2.0f, __builtin_amdgcn_rcpf(e + 1.0f), 1.0f);
}

// load 8 consecutive fp32 weights -> fp16 A-fragment slice
__device__ __forceinline__ f16x8 cvt_frag(const float* base) {
    const float4* q = reinterpret_cast<const float4*>(base);
    float4 v0 = q[0], v1 = q[1];
    f16x8 r;
    r[0] = (_Float16)v0.x; r[1] = (_Float16)v0.y;
    r[2] = (_Float16)v0.z; r[3] = (_Float16)v0.w;
    r[4] = (_Float16)v1.x; r[5] = (_Float16)v1.y;
    r[6] = (_Float16)v1.z; r[7] = (_Float16)v1.w;
    return r;
}

// Wavefront-pipelined 2-layer LSTM: waves 0-5 compute layer1(step p), waves
// 6-11 compute layer2(step p-1); 4 M-tiles per wave; ONE barrier per phase.
extern "C" __global__ void __launch_bounds__(NTHR)
__attribute__((amdgpu_waves_per_eu(3, 3)))
lstm2_pipe(const float* __restrict__ x,
           const float* __restrict__ Wih0, const float* __restrict__ Whh0,
           const float* __restrict__ bih0, const float* __restrict__ bhh0,
           const float* __restrict__ Wih1, const float* __restrict__ Whh1,
           const float* __restrict__ bih1, const float* __restrict__ bhh1,
           const float* __restrict__ Wl,   const float* __restrict__ bl,
           float* __restrict__ out)
{
    // ~144 KB LDS -> 1 block/CU; 12 waves -> 3/SIMD -> 168-VGPR budget
    __shared__ __attribute__((aligned(16))) float    x_s[NSAMP * XSTR];
    __shared__ __attribute__((aligned(16))) float    out_s[NSAMP * OSTR];
    __shared__ __attribute__((aligned(16))) _Float16 h1b[2 * HBUF];
    __shared__ __attribute__((aligned(16))) _Float16 h2b[2 * HBUF];
    __shared__ __attribute__((aligned(16))) float4   bbt1[HID];
    __shared__ __attribute__((aligned(16))) float4   bbt2[HID];

    const int tid   = threadIdx.x;
    const int lane  = tid & 63;
    const int wv    = tid >> 6;       // 0..11
    const bool isL1 = (wv < 6);       // waves 0-5: layer1; 6-11: layer2
    const int lw    = isL1 ? wv : wv - 6;   // 0..5 within role
    const int n     = lane & 15;      // MFMA col = sample
    const int kg    = lane >> 4;      // k-group 0..3
    const int blk   = blockIdx.x;

    for (int i = tid; i < NSAMP * TLEN; i += NTHR) {
        int s = i >> 10, t = i & (TLEN - 1);
        x_s[s * XSTR + t]   = x[(blk * NSAMP + s) * TLEN + t];
        out_s[s * OSTR + t] = 0.0f;
    }
    for (int i = tid; i < 2 * HBUF; i += NTHR) {
        h1b[i] = (_Float16)0.0f;
        h2b[i] = (_Float16)0.0f;
    }
    if (tid < HID) {
        bbt1[tid] = make_float4(bih0[tid]       + bhh0[tid],
                                bih0[ 96 + tid] + bhh0[ 96 + tid],
                                bih0[192 + tid] + bhh0[192 + tid],
                                bih0[288 + tid] + bhh0[288 + tid]);
        bbt2[tid] = make_float4(bih1[tid]       + bhh1[tid],
                                bih1[ 96 + tid] + bhh1[ 96 + tid],
                                bih1[192 + tid] + bhh1[192 + tid],
                                bih1[288 + tid] + bhh1[288 + tid]);
    }

    // Row-permuted weights (row' = 4*unit + gate), R17-verified fragment scheme.
    // 4 tiles/wave: A[4][6] = 96 VGPR (fits 168 budget at 3 waves/SIMD).
    f16x8 A[4][6];
    float aux[4][4];   // L1: x-path weights (4 gates); L2: [0]=Wl[u]
    #pragma unroll
    for (int mi = 0; mi < 4; ++mi) {
        const int tile = lw * 4 + mi;               // 0..23
        const int rp   = tile * 16 + n;
        const int orow = (rp & 3) * HID + (rp >> 2);   // gate*96 + unit
        const int u    = tile * 4 + kg;
        if (isL1) {
            A[mi][0] = cvt_frag(Whh0 + orow * HID +  0 + kg * 8);
            A[mi][1] = cvt_frag(Whh0 + orow * HID + 32 + kg * 8);
            A[mi][2] = cvt_frag(Whh0 + orow * HID + 64 + kg * 8);
            A[mi][3] = A[mi][0]; A[mi][4] = A[mi][1]; A[mi][5] = A[mi][2]; // unused
            aux[mi][0] = Wih0[u];           aux[mi][1] = Wih0[ 96 + u];
            aux[mi][2] = Wih0[192 + u];     aux[mi][3] = Wih0[288 + u];
        } else {
            A[mi][0] = cvt_frag(Wih1 + orow * HID +  0 + kg * 8);
            A[mi][1] = cvt_frag(Wih1 + orow * HID + 32 + kg * 8);
            A[mi][2] = cvt_frag(Wih1 + orow * HID + 64 + kg * 8);
            A[mi][3] = cvt_frag(Whh1 + orow * HID +  0 + kg * 8);
            A[mi][4] = cvt_frag(Whh1 + orow * HID + 32 + kg * 8);
            A[mi][5] = cvt_frag(Whh1 + orow * HID + 64 + kg * 8);
            aux[mi][0] = Wl[u]; aux[mi][1] = 0.f; aux[mi][2] = 0.f; aux[mi][3] = 0.f;
        }
    }

    float cst[4] = {0.f, 0.f, 0.f, 0.f};
    __syncthreads();

    #pragma unroll 1
    for (int p = 0; p <= TLEN; ++p) {
        if (isL1) {
            if (p < TLEN) {
                const _Float16* hr = h1b + (p & 1) * HBUF + n * HSTR + kg * 8;
                f16x8 B0 = *reinterpret_cast<const f16x8*>(hr);
                f16x8 B1 = *reinterpret_cast<const f16x8*>(hr + 32);
                f16x8 B2 = *reinterpret_cast<const f16x8*>(hr + 64);
                const float xt = x_s[n * XSTR + p];
                _Float16* hw = h1b + ((p + 1) & 1) * HBUF + n * HSTR + lw * 16 + kg;
                #pragma unroll
                for (int mi = 0; mi < 4; ++mi) {
                    f32x4 acc = {0.f, 0.f, 0.f, 0.f};
                    acc = __builtin_amdgcn_mfma_f32_16x16x32_f16(A[mi][0], B0, acc, 0, 0, 0);
                    acc = __builtin_amdgcn_mfma_f32_16x16x32_f16(A[mi][1], B1, acc, 0, 0, 0);
                    acc = __builtin_amdgcn_mfma_f32_16x16x32_f16(A[mi][2], B2, acc, 0, 0, 0);
                    float4 bb = bbt1[lw * 16 + mi * 4 + kg];
                    float gi = sigf(fmaf(aux[mi][0], xt, acc[0] + bb.x));
                    float gf = sigf(fmaf(aux[mi][1], xt, acc[1] + bb.y));
                    float gg = tanh_fast(fmaf(aux[mi][2], xt, acc[2] + bb.z));
                    float go = sigf(fmaf(aux[mi][3], xt, acc[3] + bb.w));
                    cst[mi] = gf * cst[mi] + gi * gg;
                    float h1v = go * tanh_fast(cst[mi]);
                    hw[mi * 4] = (_Float16)h1v;
                }
            }
        } else {
            if (p >= 1) {
                const _Float16* p1 = h1b + (p & 1) * HBUF + n * HSTR + kg * 8;
                const _Float16* p2 = h2b + ((p - 1) & 1) * HBUF + n * HSTR + kg * 8;
                f16x8 B0 = *reinterpret_cast<const f16x8*>(p1);
                f16x8 B1 = *reinterpret_cast<const f16x8*>(p1 + 32);
                f16x8 B2 = *reinterpret_cast<const f16x8*>(p1 + 64);
                f16x8 B3 = *reinterpret_cast<const f16x8*>(p2);
                f16x8 B4 = *reinterpret_cast<const f16x8*>(p2 + 32);
                f16x8 B5 = *reinterpret_cast<const f16x8*>(p2 + 64);
                _Float16* hw = h2b + (p & 1) * HBUF + n * HSTR + lw * 16 + kg;
                float po = 0.f;
                #pragma unroll
                for (int mi = 0; mi < 4; ++mi) {
                    f32x4 acc = {0.f, 0.f, 0.f, 0.f};
                    acc = __builtin_amdgcn_mfma_f32_16x16x32_f16(A[mi][0], B0, acc, 0, 0, 0);
                    acc = __builtin_amdgcn_mfma_f32_16x16x32_f16(A[mi][1], B1, acc, 0, 0, 0);
                    acc = __builtin_amdgcn_mfma_f32_16x16x32_f16(A[mi][2], B2, acc, 0, 0, 0);
                    acc = __builtin_amdgcn_mfma_f32_16x16x32_f16(A[mi][3], B3, acc, 0, 0, 0);
                    acc = __builtin_amdgcn_mfma_f32_16x16x32_f16(A[mi][4], B4, acc, 0, 0, 0);
                    acc = __builtin_amdgcn_mfma_f32_16x16x32_f16(A[mi][5], B5, acc, 0, 0, 0);
                    float4 bb = bbt2[lw * 16 + mi * 4 + kg];
                    float gi = sigf(acc[0] + bb.x);
                    float gf = sigf(acc[1] + bb.y);
                    float gg = tanh_fast(acc[2] + bb.z);
                    float go = sigf(acc[3] + bb.w);
                    cst[mi] = gf * cst[mi] + gi * gg;
                    float h2v = go * tanh_fast(cst[mi]);
                    hw[mi * 4] = (_Float16)h2v;
                    po = fmaf(aux[mi][0], h2v, po);
                }
                po += __shfl_xor(po, 16);
                po += __shfl_xor(po, 32);
                if (lane < 16) atomicAdd(&out_s[n * OSTR + (p - 1)], po);
            }
        }
        __syncthreads();
        // race audit: identical structure to R18/R20 (verified passing) --
        // every conflicting buffer access pair separated by >=1 barrier.
    }

    const float bl0 = bl[0];
    for (int i = tid; i < NSAMP * TLEN; i += NTHR) {
        int s = i >> 10, t = i & (TLEN - 1);
        out[(blk * NSAMP + s) * TLEN + t] = out_s[s * OSTR + t] + bl0;
    }
}

extern "C" void kernel_launch(void* const* d_in, const int* in_sizes, int n_in,
                              void* d_out, int out_size, void* d_ws, size_t ws_size,
                              hipStream_t stream)
{
    (void)in_sizes; (void)n_in; (void)d_ws; (void)ws_size; (void)out_size;
    const float* x    = (const float*)d_in[0];
    const float* Wih0 = (const float*)d_in[1];
    const float* Whh0 = (const float*)d_in[2];
    const float* bih0 = (const float*)d_in[3];
    const float* bhh0 = (const float*)d_in[4];
    const float* Wih1 = (const float*)d_in[5];
    const float* Whh1 = (const float*)d_in[6];
    const float* bih1 = (const float*)d_in[7];
    const float* bhh1 = (const float*)d_in[8];
    const float* Wl   = (const float*)d_in[9];
    const float* bl   = (const float*)d_in[10];

    lstm2_pipe<<<dim3(16), dim3(NTHR), 0, stream>>>(
        x, Wih0, Whh0, bih0, bhh0, Wih1, Whh1, bih1, bhh1, Wl, bl,
        (float*)d_out);
}

// Round 22
// 1094.482 us; speedup vs baseline: 1.3810x; 1.3810x over previous
//
#include <hip/hip_runtime.h>

#define TLEN   1024
#define HID    96
#define NSAMP  16
#define NTHR   512
#define CHUNK  16
#define NCHUNK (TLEN / CHUNK)   // 64
#define DEPTH  8                // ring slots per group
#define HSTR   104              // padded f16 unit stride (2-way bank max, R17-proven)
#define HBUF   (NSAMP * HSTR)
#define SLOTH  (CHUNK * NSAMP * HSTR)   // f16 elems per ring slot (53248 B)
#define XSTR   1025
#define OSTR   1025

typedef _Float16 f16x8 __attribute__((ext_vector_type(8)));
typedef float    f32x4 __attribute__((ext_vector_type(4)));

__device__ __forceinline__ float sigf(float v) {
    float e = __builtin_amdgcn_exp2f(v * -1.44269504089f);   // exp(-v)
    return __builtin_amdgcn_rcpf(1.0f + e);
}
__device__ __forceinline__ float tanh_fast(float v) {
    float e = __builtin_amdgcn_exp2f(v * 2.88539008178f);    // exp(2v)
    return fmaf(-2.0f, __builtin_amdgcn_rcpf(e + 1.0f), 1.0f);
}

__device__ __forceinline__ f16x8 cvt_frag(const float* base) {
    const float4* q = reinterpret_cast<const float4*>(base);
    float4 v0 = q[0], v1 = q[1];
    f16x8 r;
    r[0] = (_Float16)v0.x; r[1] = (_Float16)v0.y;
    r[2] = (_Float16)v0.z; r[3] = (_Float16)v0.w;
    r[4] = (_Float16)v1.x; r[5] = (_Float16)v1.y;
    r[6] = (_Float16)v1.z; r[7] = (_Float16)v1.w;
    return r;
}

// zero the flag region of d_ws each launch (graph-replay determinism)
extern "C" __global__ void zero_flags(int* p) { p[threadIdx.x] = 0; }  // 1024 ints

// Two-stage cross-block pipeline: blocks 0-15 run the layer-1 recurrence for
// sample group g=blk, publishing h1 in 16-step chunks through a global ring;
// blocks 16-31 (g=blk-16) consume chunks and run layer-2 + head, lagging by
// one chunk. Per-block issue ~halves vs the fused kernel; 32 CUs active.
extern "C" __global__ void __launch_bounds__(NTHR)
lstm2_split(const float* __restrict__ x,
            const float* __restrict__ Wih0, const float* __restrict__ Whh0,
            const float* __restrict__ bih0, const float* __restrict__ bhh0,
            const float* __restrict__ Wih1, const float* __restrict__ Whh1,
            const float* __restrict__ bih1, const float* __restrict__ bhh1,
            const float* __restrict__ Wl,   const float* __restrict__ bl,
            float* __restrict__ out, unsigned char* __restrict__ ws)
{
    // ---- LDS: 127 KB, role-dependent aliasing (stages never coexist in a block)
    __shared__ __attribute__((aligned(16))) unsigned char lds_raw[127040];
    float*    xo_s  = (float*)lds_raw;                          // S1: x_s | S2: out_s (65600 B)
    _Float16* cbuf  = (_Float16*)(lds_raw + 65600);             // S1: chunk out | S2: h1 chunk in (53248 B)
    _Float16* dbuf  = (_Float16*)(lds_raw + 65600 + 53248);     // h-recurrence double buffer (6656 B)
    float4*   btab  = (float4*)(lds_raw + 65600 + 53248 + 6656);// per-unit gate biases (1536 B)

    int*      prog     = (int*)ws;              // prog[g] at g*16 ints (64 B apart)
    int*      consumed = (int*)(ws + 2048);
    _Float16* ring     = (_Float16*)(ws + 4096);

    const int tid  = threadIdx.x;
    const int lane = tid & 63;
    const int wv   = tid >> 6;         // 0..7, owns tiles wv*3..wv*3+2
    const int n    = lane & 15;        // MFMA col = sample
    const int kg   = lane >> 4;        // k-group 0..3
    const int blk  = blockIdx.x;
    const bool isS1 = (blk < 16);
    const int g    = isS1 ? blk : blk - 16;
    _Float16* gring = ring + (size_t)g * DEPTH * SLOTH;

    // ---- init ----
    if (isS1) {
        for (int i = tid; i < NSAMP * TLEN; i += NTHR) {
            int s = i >> 10, t = i & (TLEN - 1);
            xo_s[s * XSTR + t] = x[(g * NSAMP + s) * TLEN + t];
        }
        if (tid < HID)
            btab[tid] = make_float4(bih0[tid]       + bhh0[tid],
                                    bih0[ 96 + tid] + bhh0[ 96 + tid],
                                    bih0[192 + tid] + bhh0[192 + tid],
                                    bih0[288 + tid] + bhh0[288 + tid]);
    } else {
        for (int i = tid; i < NSAMP * OSTR; i += NTHR) xo_s[i] = 0.0f;
        if (tid < HID)
            btab[tid] = make_float4(bih1[tid]       + bhh1[tid],
                                    bih1[ 96 + tid] + bhh1[ 96 + tid],
                                    bih1[192 + tid] + bhh1[192 + tid],
                                    bih1[288 + tid] + bhh1[288 + tid]);
    }
    for (int i = tid; i < 2 * HBUF; i += NTHR) dbuf[i] = (_Float16)0.0f;

    // ---- weights: row-permuted fragments (row' = 4*unit + gate), R17-verified
    f16x8 A[3][6];
    float aux[3][4];   // S1: x-path gate weights; S2: [0]=Wl[u]
    #pragma unroll
    for (int mi = 0; mi < 3; ++mi) {
        const int tile = wv * 3 + mi;                  // 0..23
        const int rp   = tile * 16 + n;
        const int orow = (rp & 3) * HID + (rp >> 2);   // gate*96 + unit
        const int u    = tile * 4 + kg;
        if (isS1) {
            A[mi][0] = cvt_frag(Whh0 + orow * HID +  0 + kg * 8);
            A[mi][1] = cvt_frag(Whh0 + orow * HID + 32 + kg * 8);
            A[mi][2] = cvt_frag(Whh0 + orow * HID + 64 + kg * 8);
            A[mi][3] = A[mi][0]; A[mi][4] = A[mi][1]; A[mi][5] = A[mi][2]; // unused
            aux[mi][0] = Wih0[u];           aux[mi][1] = Wih0[ 96 + u];
            aux[mi][2] = Wih0[192 + u];     aux[mi][3] = Wih0[288 + u];
        } else {
            A[mi][0] = cvt_frag(Wih1 + orow * HID +  0 + kg * 8);
            A[mi][1] = cvt_frag(Wih1 + orow * HID + 32 + kg * 8);
            A[mi][2] = cvt_frag(Wih1 + orow * HID + 64 + kg * 8);
            A[mi][3] = cvt_frag(Whh1 + orow * HID +  0 + kg * 8);
            A[mi][4] = cvt_frag(Whh1 + orow * HID + 32 + kg * 8);
            A[mi][5] = cvt_frag(Whh1 + orow * HID + 64 + kg * 8);
            aux[mi][0] = Wl[u]; aux[mi][1] = 0.f; aux[mi][2] = 0.f; aux[mi][3] = 0.f;
        }
    }
    float cst[3] = {0.f, 0.f, 0.f};
    __syncthreads();

    if (isS1) {
        // ================= STAGE 1: layer-1 recurrence =================
        for (int ch = 0; ch < NCHUNK; ++ch) {
            #pragma unroll 1
            for (int s = 0; s < CHUNK; ++s) {
                const int t = ch * CHUNK + s;
                const int rd = t & 1, wb = rd ^ 1;
                const _Float16* hr = dbuf + rd * HBUF + n * HSTR + kg * 8;
                f16x8 B0 = *reinterpret_cast<const f16x8*>(hr);
                f16x8 B1 = *reinterpret_cast<const f16x8*>(hr + 32);
                f16x8 B2 = *reinterpret_cast<const f16x8*>(hr + 64);
                const float xt = xo_s[n * XSTR + t];
                _Float16* hw = dbuf + wb * HBUF + n * HSTR;
                _Float16* cw = cbuf + (s * NSAMP + n) * HSTR;
                #pragma unroll
                for (int mi = 0; mi < 3; ++mi) {
                    f32x4 acc = {0.f, 0.f, 0.f, 0.f};
                    acc = __builtin_amdgcn_mfma_f32_16x16x32_f16(A[mi][0], B0, acc, 0, 0, 0);
                    acc = __builtin_amdgcn_mfma_f32_16x16x32_f16(A[mi][1], B1, acc, 0, 0, 0);
                    acc = __builtin_amdgcn_mfma_f32_16x16x32_f16(A[mi][2], B2, acc, 0, 0, 0);
                    const int up = (wv * 3 + mi) * 4 + kg;
                    float4 bb = btab[up];
                    float gi = sigf(fmaf(aux[mi][0], xt, acc[0] + bb.x));
                    float gf = sigf(fmaf(aux[mi][1], xt, acc[1] + bb.y));
                    float gg = tanh_fast(fmaf(aux[mi][2], xt, acc[2] + bb.z));
                    float go = sigf(fmaf(aux[mi][3], xt, acc[3] + bb.w));
                    cst[mi] = gf * cst[mi] + gi * gg;
                    _Float16 h1v = (_Float16)(go * tanh_fast(cst[mi]));
                    hw[up] = h1v;       // for next-step recurrence
                    cw[up] = h1v;       // for chunk export
                }
                __syncthreads();
            }
            // publish chunk: wait slot free, copy LDS->ring, fence, release
            if (tid == 0) {
                while (ch - __hip_atomic_load(&consumed[g * 16], __ATOMIC_ACQUIRE,
                                              __HIP_MEMORY_SCOPE_AGENT) >= DEPTH)
                    __builtin_amdgcn_s_sleep(2);
            }
            __syncthreads();
            {
                _Float16* slot = gring + (size_t)(ch % DEPTH) * SLOTH;
                const int4* src = (const int4*)cbuf;
                int4* dst = (int4*)slot;
                for (int i = tid; i < (int)(SLOTH * 2 / 16); i += NTHR) dst[i] = src[i];
            }
            __threadfence();     // each thread: own stores device-visible
            __syncthreads();     // all threads fenced
            if (tid == 0)
                __hip_atomic_store(&prog[g * 16], ch + 1, __ATOMIC_RELEASE,
                                   __HIP_MEMORY_SCOPE_AGENT);
        }
    } else {
        // ================= STAGE 2: layer-2 recurrence + head =================
        for (int ch = 0; ch < NCHUNK; ++ch) {
            if (tid == 0) {
                while (__hip_atomic_load(&prog[g * 16], __ATOMIC_ACQUIRE,
                                         __HIP_MEMORY_SCOPE_AGENT) < ch + 1)
                    __builtin_amdgcn_s_sleep(2);
            }
            __syncthreads();   // tid0's acquire invalidated this CU's L1
            {
                const _Float16* slot = gring + (size_t)(ch % DEPTH) * SLOTH;
                const int4* src = (const int4*)slot;
                int4* dst = (int4*)cbuf;
                for (int i = tid; i < (int)(SLOTH * 2 / 16); i += NTHR) dst[i] = src[i];
            }
            __syncthreads();
            if (tid == 0)
                __hip_atomic_store(&consumed[g * 16], ch + 1, __ATOMIC_RELEASE,
                                   __HIP_MEMORY_SCOPE_AGENT);
            #pragma unroll 1
            for (int s = 0; s < CHUNK; ++s) {
                const int t = ch * CHUNK + s;
                const int rd = t & 1, wb = rd ^ 1;
                const _Float16* p1 = cbuf + (s * NSAMP + n) * HSTR + kg * 8;
                const _Float16* p2 = dbuf + rd * HBUF + n * HSTR + kg * 8;
                f16x8 B0 = *reinterpret_cast<const f16x8*>(p1);
                f16x8 B1 = *reinterpret_cast<const f16x8*>(p1 + 32);
                f16x8 B2 = *reinterpret_cast<const f16x8*>(p1 + 64);
                f16x8 B3 = *reinterpret_cast<const f16x8*>(p2);
                f16x8 B4 = *reinterpret_cast<const f16x8*>(p2 + 32);
                f16x8 B5 = *reinterpret_cast<const f16x8*>(p2 + 64);
                _Float16* hw = dbuf + wb * HBUF + n * HSTR;
                float po = 0.f;
                #pragma unroll
                for (int mi = 0; mi < 3; ++mi) {
                    f32x4 acc = {0.f, 0.f, 0.f, 0.f};
                    acc = __builtin_amdgcn_mfma_f32_16x16x32_f16(A[mi][0], B0, acc, 0, 0, 0);
                    acc = __builtin_amdgcn_mfma_f32_16x16x32_f16(A[mi][1], B1, acc, 0, 0, 0);
                    acc = __builtin_amdgcn_mfma_f32_16x16x32_f16(A[mi][2], B2, acc, 0, 0, 0);
                    acc = __builtin_amdgcn_mfma_f32_16x16x32_f16(A[mi][3], B3, acc, 0, 0, 0);
                    acc = __builtin_amdgcn_mfma_f32_16x16x32_f16(A[mi][4], B4, acc, 0, 0, 0);
                    acc = __builtin_amdgcn_mfma_f32_16x16x32_f16(A[mi][5], B5, acc, 0, 0, 0);
                    const int up = (wv * 3 + mi) * 4 + kg;
                    float4 bb = btab[up];
                    float gi = sigf(acc[0] + bb.x);
                    float gf = sigf(acc[1] + bb.y);
                    float gg = tanh_fast(acc[2] + bb.z);
                    float go = sigf(acc[3] + bb.w);
                    cst[mi] = gf * cst[mi] + gi * gg;
                    float h2v = go * tanh_fast(cst[mi]);
                    hw[up] = (_Float16)h2v;
                    po = fmaf(aux[mi][0], h2v, po);
                }
                po += __shfl_xor(po, 16);
                po += __shfl_xor(po, 32);
                if (lane < 16) atomicAdd(&xo_s[n * OSTR + t], po);
                __syncthreads();
            }
        }
        const float bl0 = bl[0];
        for (int i = tid; i < NSAMP * TLEN; i += NTHR) {
            int s = i >> 10, t = i & (TLEN - 1);
            out[(g * NSAMP + s) * TLEN + t] = xo_s[s * OSTR + t] + bl0;
        }
    }
}

extern "C" void kernel_launch(void* const* d_in, const int* in_sizes, int n_in,
                              void* d_out, int out_size, void* d_ws, size_t ws_size,
                              hipStream_t stream)
{
    (void)in_sizes; (void)n_in; (void)ws_size; (void)out_size;
    const float* x    = (const float*)d_in[0];
    const float* Wih0 = (const float*)d_in[1];
    const float* Whh0 = (const float*)d_in[2];
    const float* bih0 = (const float*)d_in[3];
    const float* bhh0 = (const float*)d_in[4];
    const float* Wih1 = (const float*)d_in[5];
    const float* Whh1 = (const float*)d_in[6];
    const float* bih1 = (const float*)d_in[7];
    const float* bhh1 = (const float*)d_in[8];
    const float* Wl   = (const float*)d_in[9];
    const float* bl   = (const float*)d_in[10];

    zero_flags<<<dim3(1), dim3(1024), 0, stream>>>((int*)d_ws);
    lstm2_split<<<dim3(32), dim3(NTHR), 0, stream>>>(
        x, Wih0, Whh0, bih0, bhh0, Wih1, Whh1, bih1, bhh1, Wl, bl,
        (float*)d_out, (unsigned char*)d_ws);
}

// Round 23
// 1062.736 us; speedup vs baseline: 1.4223x; 1.0299x over previous
//
#include <hip/hip_runtime.h>

#define TLEN   1024
#define HID    96
#define NSAMP  16
#define NTHR   512
#define CHUNK  16
#define NCHUNK (TLEN / CHUNK)   // 64
#define DEPTH  8                // ring slots per group
#define HSTR   104              // padded f16 unit stride
#define HBUF   (NSAMP * HSTR)
#define SLICE  (NSAMP * HSTR)           // f16 per step-slice (3328 B)
#define SLICE4 208                      // int4 per slice
#define SLOTH  (CHUNK * SLICE)          // f16 per ring slot (53248 B)
#define XSTR   1025

typedef _Float16 f16x8 __attribute__((ext_vector_type(8)));
typedef float    f32x4 __attribute__((ext_vector_type(4)));

__device__ __forceinline__ float sigf(float v) {
    float e = __builtin_amdgcn_exp2f(v * -1.44269504089f);   // exp(-v)
    return __builtin_amdgcn_rcpf(1.0f + e);
}
__device__ __forceinline__ float tanh_fast(float v) {
    float e = __builtin_amdgcn_exp2f(v * 2.88539008178f);    // exp(2v)
    return fmaf(-2.0f, __builtin_amdgcn_rcpf(e + 1.0f), 1.0f);
}

__device__ __forceinline__ f16x8 cvt_frag(const float* base) {
    const float4* q = reinterpret_cast<const float4*>(base);
    float4 v0 = q[0], v1 = q[1];
    f16x8 r;
    r[0] = (_Float16)v0.x; r[1] = (_Float16)v0.y;
    r[2] = (_Float16)v0.z; r[3] = (_Float16)v0.w;
    r[4] = (_Float16)v1.x; r[5] = (_Float16)v1.y;
    r[6] = (_Float16)v1.z; r[7] = (_Float16)v1.w;
    return r;
}

extern "C" __global__ void zero_flags(int* p) { p[threadIdx.x] = 0; }  // 1024 ints

// Two-stage cross-block pipeline (R22) + fully overlapped handoff:
// S1 streams each h1 slice to the global ring DURING the next step's compute;
// S2 prefetches chunk ch+1 slice-by-slice into a double-buffered LDS chunk
// while computing chunk ch. Serial copy phases and wait bubbles vanish.
extern "C" __global__ void __launch_bounds__(NTHR)
lstm2_split(const float* __restrict__ x,
            const float* __restrict__ Wih0, const float* __restrict__ Whh0,
            const float* __restrict__ bih0, const float* __restrict__ bhh0,
            const float* __restrict__ Wih1, const float* __restrict__ Whh1,
            const float* __restrict__ bih1, const float* __restrict__ bhh1,
            const float* __restrict__ Wl,   const float* __restrict__ bl,
            float* __restrict__ out, unsigned char* __restrict__ ws)
{
    // LDS carving (role-dependent; 127 KB -> 1 block/CU, 2 waves/SIMD)
    // S1: x_s 65600 | cbuf 53248 | dbuf 6656 | btab 1536
    // S2: cb[0] 53248 | cb[1] 53248 | dbuf 6656 | btab 1536 | obuf 1088 | nf 4
    __shared__ __attribute__((aligned(16))) unsigned char lds_raw[127104];

    int*      prog     = (int*)ws;              // prog[g] at g*16 ints
    int*      consumed = (int*)(ws + 2048);
    _Float16* ring     = (_Float16*)(ws + 4096);

    const int tid  = threadIdx.x;
    const int lane = tid & 63;
    const int wv   = tid >> 6;         // 0..7, owns tiles wv*3..wv*3+2
    const int n    = lane & 15;        // MFMA col = sample
    const int kg   = lane >> 4;        // k-group 0..3
    const int blk  = blockIdx.x;
    const bool isS1 = (blk < 16);
    const int g    = isS1 ? blk : blk - 16;
    _Float16* gring = ring + (size_t)g * DEPTH * SLOTH;

    // ---- role-specific LDS pointers ----
    float*    x_s  = (float*)lds_raw;                                   // S1 only
    _Float16* cbS1 = (_Float16*)(lds_raw + 65600);                      // S1 only
    _Float16* cb0  = (_Float16*)lds_raw;                                // S2 only
    _Float16* cb1  = (_Float16*)(lds_raw + 53248);                      // S2 only
    _Float16* dbuf = (_Float16*)(lds_raw + (isS1 ? 118848 : 106496));
    float4*   btab = (float4*)(lds_raw + (isS1 ? 125504 : 113152));
    float*    obuf = (float*)(lds_raw + 114688);                        // S2: [16][17]
    int*      nf_s = (int*)(lds_raw + 115776);                          // S2 prefetch flag

    // ---- init ----
    if (isS1) {
        for (int i = tid; i < NSAMP * TLEN; i += NTHR) {
            int s = i >> 10, t = i & (TLEN - 1);
            x_s[s * XSTR + t] = x[(g * NSAMP + s) * TLEN + t];
        }
        if (tid < HID)
            btab[tid] = make_float4(bih0[tid]       + bhh0[tid],
                                    bih0[ 96 + tid] + bhh0[ 96 + tid],
                                    bih0[192 + tid] + bhh0[192 + tid],
                                    bih0[288 + tid] + bhh0[288 + tid]);
    } else {
        if (tid < HID)
            btab[tid] = make_float4(bih1[tid]       + bhh1[tid],
                                    bih1[ 96 + tid] + bhh1[ 96 + tid],
                                    bih1[192 + tid] + bhh1[192 + tid],
                                    bih1[288 + tid] + bhh1[288 + tid]);
    }
    for (int i = tid; i < 2 * HBUF; i += NTHR) dbuf[i] = (_Float16)0.0f;

    // ---- weights: row-permuted fragments (row' = 4*unit + gate), R17-verified
    f16x8 A[3][6];
    float aux[3][4];
    #pragma unroll
    for (int mi = 0; mi < 3; ++mi) {
        const int tile = wv * 3 + mi;
        const int rp   = tile * 16 + n;
        const int orow = (rp & 3) * HID + (rp >> 2);   // gate*96 + unit
        const int u    = tile * 4 + kg;
        if (isS1) {
            A[mi][0] = cvt_frag(Whh0 + orow * HID +  0 + kg * 8);
            A[mi][1] = cvt_frag(Whh0 + orow * HID + 32 + kg * 8);
            A[mi][2] = cvt_frag(Whh0 + orow * HID + 64 + kg * 8);
            A[mi][3] = A[mi][0]; A[mi][4] = A[mi][1]; A[mi][5] = A[mi][2]; // unused
            aux[mi][0] = Wih0[u];           aux[mi][1] = Wih0[ 96 + u];
            aux[mi][2] = Wih0[192 + u];     aux[mi][3] = Wih0[288 + u];
        } else {
            A[mi][0] = cvt_frag(Wih1 + orow * HID +  0 + kg * 8);
            A[mi][1] = cvt_frag(Wih1 + orow * HID + 32 + kg * 8);
            A[mi][2] = cvt_frag(Wih1 + orow * HID + 64 + kg * 8);
            A[mi][3] = cvt_frag(Whh1 + orow * HID +  0 + kg * 8);
            A[mi][4] = cvt_frag(Whh1 + orow * HID + 32 + kg * 8);
            A[mi][5] = cvt_frag(Whh1 + orow * HID + 64 + kg * 8);
            aux[mi][0] = Wl[u]; aux[mi][1] = 0.f; aux[mi][2] = 0.f; aux[mi][3] = 0.f;
        }
    }
    float cst[3] = {0.f, 0.f, 0.f};
    __syncthreads();

    if (isS1) {
        // ================= STAGE 1 =================
        for (int ch = 0; ch < NCHUNK; ++ch) {
            if (tid == 0) {
                while (ch - __hip_atomic_load(&consumed[g * 16], __ATOMIC_ACQUIRE,
                                              __HIP_MEMORY_SCOPE_AGENT) >= DEPTH)
                    __builtin_amdgcn_s_sleep(2);
            }
            __syncthreads();
            _Float16* slot = gring + (size_t)(ch % DEPTH) * SLOTH;
            #pragma unroll 1
            for (int s = 0; s < CHUNK; ++s) {
                // overlapped handoff: ship slice s-1 while computing step s
                if (s > 0 && tid < SLICE4) {
                    const int4* src = (const int4*)(cbS1 + (s - 1) * SLICE);
                    int4* dst = (int4*)(slot + (s - 1) * SLICE);
                    dst[tid] = src[tid];
                }
                const int t = ch * CHUNK + s;
                const int rd = t & 1, wb = rd ^ 1;
                const _Float16* hr = dbuf + rd * HBUF + n * HSTR + kg * 8;
                f16x8 B0 = *reinterpret_cast<const f16x8*>(hr);
                f16x8 B1 = *reinterpret_cast<const f16x8*>(hr + 32);
                f16x8 B2 = *reinterpret_cast<const f16x8*>(hr + 64);
                const float xt = x_s[n * XSTR + t];
                _Float16* hw = dbuf + wb * HBUF + n * HSTR;
                _Float16* cw = cbS1 + s * SLICE + n * HSTR;
                #pragma unroll
                for (int mi = 0; mi < 3; ++mi) {
                    f32x4 acc = {0.f, 0.f, 0.f, 0.f};
                    acc = __builtin_amdgcn_mfma_f32_16x16x32_f16(A[mi][0], B0, acc, 0, 0, 0);
                    acc = __builtin_amdgcn_mfma_f32_16x16x32_f16(A[mi][1], B1, acc, 0, 0, 0);
                    acc = __builtin_amdgcn_mfma_f32_16x16x32_f16(A[mi][2], B2, acc, 0, 0, 0);
                    const int up = (wv * 3 + mi) * 4 + kg;
                    float4 bb = btab[up];
                    float gi = sigf(fmaf(aux[mi][0], xt, acc[0] + bb.x));
                    float gf = sigf(fmaf(aux[mi][1], xt, acc[1] + bb.y));
                    float gg = tanh_fast(fmaf(aux[mi][2], xt, acc[2] + bb.z));
                    float go = sigf(fmaf(aux[mi][3], xt, acc[3] + bb.w));
                    cst[mi] = gf * cst[mi] + gi * gg;
                    _Float16 h1v = (_Float16)(go * tanh_fast(cst[mi]));
                    hw[up] = h1v;
                    cw[up] = h1v;
                }
                __syncthreads();
            }
            if (tid < SLICE4) {   // last slice
                const int4* src = (const int4*)(cbS1 + 15 * SLICE);
                int4* dst = (int4*)(slot + 15 * SLICE);
                dst[tid] = src[tid];
            }
            __threadfence();
            __syncthreads();
            if (tid == 0)
                __hip_atomic_store(&prog[g * 16], ch + 1, __ATOMIC_RELEASE,
                                   __HIP_MEMORY_SCOPE_AGENT);
        }
    } else {
        // ================= STAGE 2 =================
        const float bl0 = bl[0];
        int cur = 0;
        bool have = false;
        for (int ch = 0; ch < NCHUNK; ++ch) {
            _Float16* ccur = cur ? cb1 : cb0;
            _Float16* cnxt = cur ? cb0 : cb1;
            if (!have) {   // startup / fallback: blocking fetch of chunk ch
                if (tid == 0) {
                    while (__hip_atomic_load(&prog[g * 16], __ATOMIC_ACQUIRE,
                                             __HIP_MEMORY_SCOPE_AGENT) < ch + 1)
                        __builtin_amdgcn_s_sleep(2);
                }
                __syncthreads();
                const _Float16* slot = gring + (size_t)(ch % DEPTH) * SLOTH;
                const int4* src = (const int4*)slot;
                int4* dst = (int4*)ccur;
                for (int i = tid; i < CHUNK * SLICE4; i += NTHR) dst[i] = src[i];
                __syncthreads();
                if (tid == 0)
                    __hip_atomic_store(&consumed[g * 16], ch + 1, __ATOMIC_RELEASE,
                                       __HIP_MEMORY_SCOPE_AGENT);
            }
            if (tid < CHUNK * 17) obuf[tid] = 0.0f;
            if (tid == 0) {
                int r = 0;
                if (ch + 1 < NCHUNK)
                    r = (__hip_atomic_load(&prog[g * 16], __ATOMIC_ACQUIRE,
                                           __HIP_MEMORY_SCOPE_AGENT) >= ch + 2) ? 1 : 0;
                *nf_s = r;
            }
            __syncthreads();
            const bool pf = (*nf_s != 0);
            const _Float16* nslot = gring + (size_t)((ch + 1) % DEPTH) * SLOTH;
            #pragma unroll 1
            for (int s = 0; s < CHUNK; ++s) {
                // overlapped prefetch of next chunk's slice s
                if (pf && tid < SLICE4) {
                    const int4* src = (const int4*)(nslot + s * SLICE);
                    int4* dst = (int4*)(cnxt + s * SLICE);
                    dst[tid] = src[tid];
                }
                const int t = ch * CHUNK + s;
                const int rd = t & 1, wb = rd ^ 1;
                const _Float16* p1 = ccur + s * SLICE + n * HSTR + kg * 8;
                const _Float16* p2 = dbuf + rd * HBUF + n * HSTR + kg * 8;
                f16x8 B0 = *reinterpret_cast<const f16x8*>(p1);
                f16x8 B1 = *reinterpret_cast<const f16x8*>(p1 + 32);
                f16x8 B2 = *reinterpret_cast<const f16x8*>(p1 + 64);
                f16x8 B3 = *reinterpret_cast<const f16x8*>(p2);
                f16x8 B4 = *reinterpret_cast<const f16x8*>(p2 + 32);
                f16x8 B5 = *reinterpret_cast<const f16x8*>(p2 + 64);
                _Float16* hw = dbuf + wb * HBUF + n * HSTR;
                float po = 0.f;
                #pragma unroll
                for (int mi = 0; mi < 3; ++mi) {
                    f32x4 acc = {0.f, 0.f, 0.f, 0.f};
                    acc = __builtin_amdgcn_mfma_f32_16x16x32_f16(A[mi][0], B0, acc, 0, 0, 0);
                    acc = __builtin_amdgcn_mfma_f32_16x16x32_f16(A[mi][1], B1, acc, 0, 0, 0);
                    acc = __builtin_amdgcn_mfma_f32_16x16x32_f16(A[mi][2], B2, acc, 0, 0, 0);
                    acc = __builtin_amdgcn_mfma_f32_16x16x32_f16(A[mi][3], B3, acc, 0, 0, 0);
                    acc = __builtin_amdgcn_mfma_f32_16x16x32_f16(A[mi][4], B4, acc, 0, 0, 0);
                    acc = __builtin_amdgcn_mfma_f32_16x16x32_f16(A[mi][5], B5, acc, 0, 0, 0);
                    const int up = (wv * 3 + mi) * 4 + kg;
                    float4 bb = btab[up];
                    float gi = sigf(acc[0] + bb.x);
                    float gf = sigf(acc[1] + bb.y);
                    float gg = tanh_fast(acc[2] + bb.z);
                    float go = sigf(acc[3] + bb.w);
                    cst[mi] = gf * cst[mi] + gi * gg;
                    float h2v = go * tanh_fast(cst[mi]);
                    hw[up] = (_Float16)h2v;
                    po = fmaf(aux[mi][0], h2v, po);
                }
                po += __shfl_xor(po, 16);
                po += __shfl_xor(po, 32);
                if (lane < 16) atomicAdd(&obuf[s * 17 + n], po);
                __syncthreads();
            }
            // flush this chunk's outputs (obuf complete per the last barrier)
            if (tid < 256) {
                int s = tid & 15, j = tid >> 4;
                out[(g * NSAMP + j) * TLEN + ch * CHUNK + s] = obuf[s * 17 + j] + bl0;
            }
            if (pf) {
                if (tid == 0)
                    __hip_atomic_store(&consumed[g * 16], ch + 2, __ATOMIC_RELEASE,
                                       __HIP_MEMORY_SCOPE_AGENT);
                cur ^= 1;
                have = true;
            } else {
                have = false;
            }
            __syncthreads();   // flush reads done before next chunk zeroes obuf
        }
    }
}

extern "C" void kernel_launch(void* const* d_in, const int* in_sizes, int n_in,
                              void* d_out, int out_size, void* d_ws, size_t ws_size,
                              hipStream_t stream)
{
    (void)in_sizes; (void)n_in; (void)ws_size; (void)out_size;
    const float* x    = (const float*)d_in[0];
    const float* Wih0 = (const float*)d_in[1];
    const float* Whh0 = (const float*)d_in[2];
    const float* bih0 = (const float*)d_in[3];
    const float* bhh0 = (const float*)d_in[4];
    const float* Wih1 = (const float*)d_in[5];
    const float* Whh1 = (const float*)d_in[6];
    const float* bih1 = (const float*)d_in[7];
    const float* bhh1 = (const float*)d_in[8];
    const float* Wl   = (const float*)d_in[9];
    const float* bl   = (const float*)d_in[10];

    zero_flags<<<dim3(1), dim3(1024), 0, stream>>>((int*)d_ws);
    lstm2_split<<<dim3(32), dim3(NTHR), 0, stream>>>(
        x, Wih0, Whh0, bih0, bhh0, Wih1, Whh1, bih1, bhh1, Wl, bl,
        (float*)d_out, (unsigned char*)d_ws);
}